// Round 7
// baseline (891.870 us; speedup 1.0000x reference)
//
#include <hip/hip_runtime.h>

// FlowNet correlation: out[b, dy*9+dx, y, x] = (1/256) sum_c x1[b,c,y,x] * x2[b,c,y+dy-4,x+dx-4]
// B=4 C=256 H=W=128, 9x9 displacements, zero padding.
//
// Round-11: DROP LDS STAGING ENTIRELY - direct global->reg streaming.
// Rationale: r4-r10 proved the LDS-staged structure is pinned at 102-108 us
// (VALUBusy 29%, Occ 21%) against a 17 us FMA floor; occupancy (r5/7/8),
// issue placement (r9) and vmcnt-counted barriers (r10) all null/negative.
// The stall is the dependency structure: global->reg->LDS->reg legs + a
// barrier every 4 channels, at a structural 9 waves/CU (2304 waves total).
// Key fact: per lane dy is FIXED -> each lane only ever reads ONE x2 image
// row (y0+gy+dy-4), advancing by HW per channel; its 12-dw window = 3
// aligned float4s whose validity is 3 loop-invariant bools (starts = 0 mod 4,
// W=128 -> all-in or all-out). So per channel: 1 x1 float4 + 3 x2 float4
// direct from global (L1/L2: 3 waves/block share 15/16 x2 rows + all x1;
// g-siblings share via XCD swizzle) + 36 FMA. No barriers, no LDS ->
// compiler free to software-pipeline channels (ILP replaces capped TLP).
// Kept validated: lane map gy=lane>>2 (coalesced), XCD swizzle, epilogue,
// launch_bounds(192,4) (no spill at ~90 VGPR).

#define MD 4
constexpr int Bc = 4, Cc = 256, Hc = 128, Wc = 128;
constexpr int HW = Hc * Wc;
constexpr int TH = 16, TW = 16;
constexpr int NTHR = 192;

__global__ __launch_bounds__(NTHR, 4)
void corr_kernel(const float* __restrict__ x1, const float* __restrict__ x2,
                 float* __restrict__ out)
{
    const int tid  = threadIdx.x;
    const int w    = tid >> 6;          // wave id = local dy
    const int lane = tid & 63;
    const int gy   = lane >> 2;         // 0..15 tile row
    const int gx   = lane & 3;          // 0..3  col-group (4 px each)

    // ---- XCD-aware swizzle: g-siblings (same tile) differ by +8 in bid -> same XCD ----
    const int bid  = blockIdx.x;
    const int q    = bid / 24;
    const int r    = bid - q * 24;
    const int g    = r >> 3;            // d-group 0..2
    const int t    = q * 8 + (r & 7);   // tile index 0..255
    const int tx = t & 7;
    const int ty = (t >> 3) & 7;
    const int bb = t >> 6;
    const int x0 = tx * TW, y0 = ty * TH;

    const int dy   = 3 * g + w;                 // 0..8
    const int row  = y0 + gy + dy - MD;         // the ONE x2 row this lane reads
    const bool rv  = (unsigned)row < (unsigned)Hc;
    const int rowc = rv ? row : 0;              // clamped for address formation
    const int wst  = x0 + 4 * gx - MD;          // window start col (= 0 mod 4)
    const bool v0  = rv && ((unsigned)(wst + 0) < (unsigned)Wc);
    const bool v1  = rv && ((unsigned)(wst + 4) < (unsigned)Wc);
    const bool v2  = rv && ((unsigned)(wst + 8) < (unsigned)Wc);

    const float* x1p = x1 + (((size_t)bb * Cc) * Hc + (y0 + gy)) * Wc + x0 + 4 * gx;
    const float* x2p = x2 + (((size_t)bb * Cc) * Hc + rowc) * Wc + wst;

    float acc[9][4];
    #pragma unroll
    for (int dx = 0; dx < 9; ++dx)
        #pragma unroll
        for (int p = 0; p < 4; ++p) acc[dx][p] = 0.f;

    const float4 f40 = make_float4(0.f, 0.f, 0.f, 0.f);

    // ---- channel loop: 4 independent float4 loads + 36 FMA per channel.
    //      No barriers/LDS: compiler software-pipelines across iterations. ----
    #pragma unroll 2
    for (int c = 0; c < Cc; ++c) {
        const size_t co = (size_t)c * HW;
        const float4 a4 = *(const float4*)(x1p + co);
        const float4 r0 = v0 ? *(const float4*)(x2p + co)     : f40;
        const float4 r1 = v1 ? *(const float4*)(x2p + co + 4) : f40;
        const float4 r2 = v2 ? *(const float4*)(x2p + co + 8) : f40;
        const float v[12] = {r0.x, r0.y, r0.z, r0.w,
                             r1.x, r1.y, r1.z, r1.w,
                             r2.x, r2.y, r2.z, r2.w};
        const float a[4] = {a4.x, a4.y, a4.z, a4.w};
        #pragma unroll
        for (int dx = 0; dx < 9; ++dx)
            #pragma unroll
            for (int p = 0; p < 4; ++p)
                acc[dx][p] += a[p] * v[dx + p];
    }

    // ---- epilogue: scale and store 9 aligned float4 per thread (validated r4) ----
    const float inv = 1.0f / (float)Cc;
    float* ob = out + (((size_t)bb * 81 + dy * 9) * Hc + (y0 + gy)) * Wc + x0 + 4 * gx;
    #pragma unroll
    for (int dx = 0; dx < 9; ++dx) {
        float4 st = make_float4(acc[dx][0] * inv, acc[dx][1] * inv,
                                acc[dx][2] * inv, acc[dx][3] * inv);
        *(float4*)(ob + dx * HW) = st;
    }
}

extern "C" void kernel_launch(void* const* d_in, const int* in_sizes, int n_in,
                              void* d_out, int out_size, void* d_ws, size_t ws_size,
                              hipStream_t stream) {
    const float* x1 = (const float*)d_in[0];
    const float* x2 = (const float*)d_in[1];
    float* out = (float*)d_out;
    dim3 grid(3 * 8 * 8 * Bc), block(NTHR);   // 768 blocks x 192 threads
    corr_kernel<<<grid, block, 0, stream>>>(x1, x2, out);
}

// Round 8
// 204.934 us; speedup vs baseline: 4.3520x; 4.3520x over previous
//
#include <hip/hip_runtime.h>

// FlowNet correlation: out[b, dy*9+dx, y, x] = (1/256) sum_c x1[b,c,y,x] * x2[b,c,y+dy-4,x+dx-4]
// B=4 C=256 H=W=128, 9x9 displacements, zero padding.
//
// Round-12: 8-px/lane wide tile (32x16) + cross-block channel split.
// Ledger: r4 structure pinned at ~102 us; occupancy x2 (r7~94 clean-equiv),
// issue placement (r9), lgkm-only barrier (r10) all ~null; no-LDS (r11) 8x worse.
// No pipe >40% -> per-chunk serialization of LDS + VALU + global latency.
// Lever: per-wave arithmetic intensity. 8 px/lane: 16-dw window (4 ds_read_b128)
// feeds 72 FMA = 0.22 LDS-dw/FMA (r4: 0.33). LDS pipe/CU ~35 -> ~28 us and each
// barrier covers 2x FMA. 8px/lane + 3-wave blocks => 384 tiles, so channels are
// split 2-way ACROSS blocks (h): grid 768 = 3 balanced blocks/CU, partials to
// d_ws, + a tiny fp32 reduce kernel. Fallback (ws too small): nh=1, grid 384.
// Bank math at 8-lane cycle-group level (r7 lesson): RSC=44, read starts
// (44*gy + 8*gx) mod 32 = {0,8,16,24 | 12,20,28,4} all distinct -> conflict-free;
// staging writes (4*gc) mod 32 <=2-way (free, m136). CC=2 keeps 144 FMA/barrier
// and acc72+nf8 ~ 120 VGPR; launch_bounds(192,3) guarantees residency, no r5 cliff.

#define MD 4
constexpr int Bc = 4, Cc = 256, Hc = 128, Wc = 128;
constexpr int HW = Hc * Wc;
constexpr int TH = 16, TW = 32;
constexpr int NDY = 3;                   // dy per d-group (one per wave)
constexpr int CC = 2;                    // channels per chunk
constexpr int SROWS = TH + NDY - 1;      // 18 staged rows
constexpr int SCOLS = TW + 2 * MD;       // 40 staged cols
constexpr int RSC = 44;                  // padded row stride (dw), conflict-free (see above)
constexpr int CH_STRIDE = SROWS * RSC;   // 792 dw per channel
constexpr int BUF_DW = CC * CH_STRIDE;   // 1584 dw per buffer
constexpr int NF4 = CC * SROWS * (SCOLS / 4);  // 180*2 = 360 float4 staging slots
constexpr int NTHR = 192;
constexpr int NSLOT = 2;                 // ceil(360/192)
constexpr long long OUTNLL = (long long)Bc * 81 * HW;   // 5,308,416 floats

__global__ __launch_bounds__(NTHR, 3)
void corr_kernel(const float* __restrict__ x1, const float* __restrict__ x2,
                 float* __restrict__ dst, int nh, float scl)
{
    __shared__ float stg[2 * BUF_DW];    // 12672 B

    const int tid  = threadIdx.x;
    const int w    = tid >> 6;           // wave id = local dy
    const int lane = tid & 63;
    const int gy   = lane >> 2;          // 0..15 tile row
    const int gx   = lane & 3;           // 0..3 col-group (8 px each)

    // ---- XCD-aware swizzle: g-siblings (+8) and h-siblings (+96) share an XCD ----
    const int bid  = blockIdx.x;
    const int q    = bid / 24;
    const int r    = bid - q * 24;
    const int g    = r >> 3;             // d-group 0..2
    const int t    = q * 8 + (r & 7);    // tile index (0..255 split / 0..127 fallback)
    const int tx   = t & 3;
    const int ty   = (t >> 2) & 7;
    const int rest = t >> 5;
    const int hh   = (nh == 2) ? (rest & 1) : 0;   // channel half
    const int bb   = (nh == 2) ? (rest >> 1) : rest;
    const int x0 = tx * TW, y0 = ty * TH;
    const int rowbase = y0 + 3 * g - MD;           // global y of staged row 0
    const int CN = Cc / nh;                        // channels this block
    const int NK = CN / CC;                        // chunks
    const int c0 = hh * CN;

    // ---- hoisted staging slot descriptors (fixed per thread across chunks) ----
    // slot = cl*180 + rr*10 + gc  (gc fastest -> write starts 4*gc: <=2-way, free)
    int  s_goff[NSLOT], s_loff[NSLOT];
    bool s_val[NSLOT], s_act[NSLOT];
    #pragma unroll
    for (int s = 0; s < NSLOT; ++s) {
        int idx = tid + s * NTHR;
        bool active = idx < NF4;
        int i2  = active ? idx : 0;
        int cl  = i2 / (SROWS * 10);
        int rem = i2 - cl * (SROWS * 10);
        int rr  = rem / 10;
        int gc  = rem - rr * 10;
        int yy  = rowbase + rr;
        int xx  = x0 - 4 + 4 * gc;       // multiple of 4: float4 all-valid or all-invalid
        s_act[s]  = active;
        s_val[s]  = active && ((unsigned)yy < (unsigned)Hc) && ((unsigned)xx < (unsigned)(Wc - 3));
        s_goff[s] = cl * HW + yy * Wc + xx;
        s_loff[s] = cl * CH_STRIDE + rr * RSC + 4 * gc;
    }

    const float* x2b = x2 + ((size_t)bb * Cc + c0) * HW;
    const float* x1b = x1 + ((size_t)bb * Cc + c0) * HW + (y0 + gy) * Wc + x0 + 8 * gx;

    float acc[9][8];
    #pragma unroll
    for (int dx = 0; dx < 9; ++dx)
        #pragma unroll
        for (int p = 0; p < 8; ++p) acc[dx][p] = 0.f;

    const float4 f40 = make_float4(0.f, 0.f, 0.f, 0.f);
    float4 nf[NSLOT];

    // ---- prologue: stage chunk 0 into buffer 0 ----
    #pragma unroll
    for (int s = 0; s < NSLOT; ++s) {
        nf[s] = f40;
        if (s_val[s]) nf[s] = *(const float4*)(x2b + s_goff[s]);
    }
    #pragma unroll
    for (int s = 0; s < NSLOT; ++s)
        if (s_act[s]) *(float4*)(&stg[s_loff[s]]) = nf[s];

    for (int k = 0; k < NK; ++k) {
        const int pb = k & 1;
        // issue global x2 prefetch for chunk k+1 (r4-validated ordering)
        if (k + 1 < NK) {
            const int gof = (k + 1) * CC * HW;
            #pragma unroll
            for (int s = 0; s < NSLOT; ++s) {
                nf[s] = f40;
                if (s_val[s]) nf[s] = *(const float4*)(x2b + gof + s_goff[s]);
            }
        }
        __syncthreads();   // chunk k's buffer fully written; prev buffer's readers done
        // ---- compute chunk k: per channel 4 ds_read_b128 (16-dw window) -> 72 FMA ----
        #pragma unroll
        for (int cl = 0; cl < CC; ++cl) {
            const int c = k * CC + cl;
            const float* xp = x1b + (size_t)c * HW;
            const float4 a0 = *(const float4*)(xp);
            const float4 a1 = *(const float4*)(xp + 4);
            const float* rowp = &stg[pb * BUF_DW + cl * CH_STRIDE + (gy + w) * RSC + 8 * gx];
            const float4 q0 = *(const float4*)(rowp);
            const float4 q1 = *(const float4*)(rowp + 4);
            const float4 q2 = *(const float4*)(rowp + 8);
            const float4 q3 = *(const float4*)(rowp + 12);
            const float v[16] = {q0.x, q0.y, q0.z, q0.w,  q1.x, q1.y, q1.z, q1.w,
                                 q2.x, q2.y, q2.z, q2.w,  q3.x, q3.y, q3.z, q3.w};
            const float a[8] = {a0.x, a0.y, a0.z, a0.w,  a1.x, a1.y, a1.z, a1.w};
            #pragma unroll
            for (int dx = 0; dx < 9; ++dx)
                #pragma unroll
                for (int p = 0; p < 8; ++p)
                    acc[dx][p] += a[p] * v[dx + p];
        }
        // ---- commit prefetched chunk k+1 ----
        if (k + 1 < NK) {
            const int lb = ((k + 1) & 1) * BUF_DW;
            #pragma unroll
            for (int s = 0; s < NSLOT; ++s)
                if (s_act[s]) *(float4*)(&stg[lb + s_loff[s]]) = nf[s];
        }
    }

    // ---- epilogue: scale (inv or 1.0) and store 9 x 2 aligned float4 ----
    float* ob = dst + (size_t)hh * OUTNLL
              + (((size_t)bb * 81 + (3 * g + w) * 9) * Hc + (y0 + gy)) * Wc + x0 + 8 * gx;
    #pragma unroll
    for (int dx = 0; dx < 9; ++dx) {
        float4 s0 = make_float4(acc[dx][0] * scl, acc[dx][1] * scl,
                                acc[dx][2] * scl, acc[dx][3] * scl);
        float4 s1 = make_float4(acc[dx][4] * scl, acc[dx][5] * scl,
                                acc[dx][6] * scl, acc[dx][7] * scl);
        *(float4*)(ob + dx * HW)     = s0;
        *(float4*)(ob + dx * HW + 4) = s1;
    }
}

// out = (wsA + wsB) * inv, float4-wise grid-stride. ~64 MB traffic, BW-bound.
__global__ __launch_bounds__(256)
void reduce_kernel(const float* __restrict__ ws, float* __restrict__ out, float scl)
{
    const long long N4 = OUTNLL / 4;
    const float4* pa = (const float4*)ws;
    const float4* pb = (const float4*)(ws + OUTNLL);
    float4* po = (float4*)out;
    long long i = (long long)blockIdx.x * 256 + threadIdx.x;
    const long long step = (long long)gridDim.x * 256;
    for (; i < N4; i += step) {
        float4 a = pa[i], b = pb[i];
        po[i] = make_float4((a.x + b.x) * scl, (a.y + b.y) * scl,
                            (a.z + b.z) * scl, (a.w + b.w) * scl);
    }
}

extern "C" void kernel_launch(void* const* d_in, const int* in_sizes, int n_in,
                              void* d_out, int out_size, void* d_ws, size_t ws_size,
                              hipStream_t stream) {
    const float* x1 = (const float*)d_in[0];
    const float* x2 = (const float*)d_in[1];
    float* out = (float*)d_out;
    const float inv = 1.0f / (float)Cc;
    const size_t need = (size_t)(2 * OUTNLL) * sizeof(float);   // 42.5 MB partials
    if (d_ws != nullptr && ws_size >= need) {
        float* ws = (float*)d_ws;
        dim3 grid(24 * 32), block(NTHR);          // 768 blocks: 4xt*8yt*4b*2h * 3g
        corr_kernel<<<grid, block, 0, stream>>>(x1, x2, ws, 2, 1.0f);
        reduce_kernel<<<dim3(2048), dim3(256), 0, stream>>>(ws, out, inv);
    } else {
        dim3 grid(24 * 16), block(NTHR);          // 384 blocks: 4xt*8yt*4b * 3g
        corr_kernel<<<grid, block, 0, stream>>>(x1, x2, out, 1, inv);
    }
}